// Round 1
// baseline (335.211 us; speedup 1.0000x reference)
//
#include <hip/hip_runtime.h>
#include <hip/hip_bf16.h>

#define N_ROWS 32768
#define D_INP  256
#define NEXP   32
#define D_OUTP 256

typedef __attribute__((ext_vector_type(4))) float f32x4;
typedef __attribute__((ext_vector_type(8))) short bf16x8;

__device__ inline unsigned short f2b(float f) {
    union { __hip_bfloat16 h; unsigned short u; } cv;
    cv.h = __float2bfloat16(f);
    return cv.u;
}

// ---------------------------------------------------------------------------
// Kernel 1: gate logits (fp32) + softmax + top-2 + per-expert sums/counts,
// fused with bf16 cast of x. 8 rows per 256-thread block; each 32-lane
// half-wave group owns one row (lane = expert).
// ---------------------------------------------------------------------------
__global__ __launch_bounds__(256) void gate_kernel(
    const float* __restrict__ x, const float* __restrict__ noise,
    const float* __restrict__ gw, const float* __restrict__ gb,
    unsigned short* __restrict__ xb, float* __restrict__ tkp,
    int* __restrict__ tki, float* __restrict__ esum, int* __restrict__ ecnt)
{
    __shared__ float xs[8 * D_INP];
    __shared__ float lsum[NEXP];
    __shared__ int   lcnt[NEXP];
    int tid = threadIdx.x;
    if (tid < NEXP) { lsum[tid] = 0.f; lcnt[tid] = 0; }
    int row0 = blockIdx.x * 8;
    const float4* xg = (const float4*)(x + (size_t)row0 * D_INP);
    float4* xs4 = (float4*)xs;
    xs4[tid]       = xg[tid];
    xs4[tid + 256] = xg[tid + 256];
    __syncthreads();

    // bf16 cast of the 8 staged rows (8 elems/thread, 16B stores)
    {
        unsigned short t[8];
        #pragma unroll
        for (int i = 0; i < 8; i++) t[i] = f2b(xs[tid * 8 + i]);
        ushort4* dst = (ushort4*)(xb + (size_t)row0 * D_INP);
        dst[tid * 2]     = *(ushort4*)&t[0];
        dst[tid * 2 + 1] = *(ushort4*)&t[4];
    }

    int r = tid >> 5, e = tid & 31;
    int grow = row0 + r;
    const float4* wr = (const float4*)(gw + (size_t)e * D_INP);
    const float4* xr = (const float4*)(xs + r * D_INP);
    float a0 = 0.f, a1 = 0.f, a2 = 0.f, a3 = 0.f;
    #pragma unroll
    for (int i = 0; i < 64; i++) {
        float4 w = wr[i], v = xr[i];
        a0 += w.x * v.x; a1 += w.y * v.y; a2 += w.z * v.z; a3 += w.w * v.w;
    }
    float logit = (a0 + a1) + (a2 + a3) + gb[e] + 0.1f * noise[(size_t)grow * NEXP + e];

    // softmax over the 32 lanes of this row-group
    float m = logit;
    #pragma unroll
    for (int s = 16; s > 0; s >>= 1) m = fmaxf(m, __shfl_xor(m, s, 32));
    float p = expf(logit - m);
    float sum = p;
    #pragma unroll
    for (int s = 16; s > 0; s >>= 1) sum += __shfl_xor(sum, s, 32);
    p /= sum;

    // top-1 (ties -> lower index, matching jax.lax.top_k)
    float bp = p; int bi = e;
    #pragma unroll
    for (int s = 16; s > 0; s >>= 1) {
        float op = __shfl_xor(bp, s, 32); int oi = __shfl_xor(bi, s, 32);
        if (op > bp || (op == bp && oi < bi)) { bp = op; bi = oi; }
    }
    // top-2
    float q = (e == bi) ? -1.f : p;
    float bp2 = q; int bi2 = e;
    #pragma unroll
    for (int s = 16; s > 0; s >>= 1) {
        float op = __shfl_xor(bp2, s, 32); int oi = __shfl_xor(bi2, s, 32);
        if (op > bp2 || (op == bp2 && oi < bi2)) { bp2 = op; bi2 = oi; }
    }
    if (e == 0) {
        tkp[grow * 2]     = bp;  tkp[grow * 2 + 1] = bp2;
        tki[grow * 2]     = bi;  tki[grow * 2 + 1] = bi2;
        atomicAdd(&lcnt[bi], 1); atomicAdd(&lcnt[bi2], 1);
    }
    atomicAdd(&lsum[e], p);
    __syncthreads();
    if (tid < NEXP) {
        unsafeAtomicAdd(&esum[tid], lsum[tid]);
        atomicAdd(&ecnt[tid], lcnt[tid]);
    }
}

// ---------------------------------------------------------------------------
// Kernel 2: experts_w fp32 -> bf16
// ---------------------------------------------------------------------------
__global__ __launch_bounds__(256) void cast_w_kernel(
    const float* __restrict__ w, unsigned short* __restrict__ wb)
{
    size_t i = (size_t)blockIdx.x * 256 + threadIdx.x; // one float4 each
    float4 v = ((const float4*)w)[i];
    unsigned short t[4] = { f2b(v.x), f2b(v.y), f2b(v.z), f2b(v.w) };
    ((ushort4*)wb)[i] = *(ushort4*)t;
}

// ---------------------------------------------------------------------------
// Kernel 3: prefix sums (row offsets + tile offsets) and load-balance loss
// ---------------------------------------------------------------------------
__global__ void scan_kernel(const float* __restrict__ esum, const int* __restrict__ ecnt,
                            int* __restrict__ offs, int* __restrict__ cursor,
                            int* __restrict__ toff, float* __restrict__ loss_out)
{
    int t = threadIdx.x;
    if (t == 0) {
        int acc = 0, ta = 0;
        for (int e = 0; e < NEXP; e++) {
            offs[e] = acc; cursor[e] = acc; toff[e] = ta;
            int c = ecnt[e];
            acc += c; ta += (c + 63) >> 6;
        }
        offs[NEXP] = acc; toff[NEXP] = ta;
    }
    if (t < 32) {
        float d = esum[t] * (1.f / N_ROWS) - (1.f / NEXP);
        float v = d * d;
        #pragma unroll
        for (int s = 16; s > 0; s >>= 1) v += __shfl_xor(v, s, 32);
        if (t == 0) *loss_out = v;  // mean((m-1/E)^2)*E == sum
    }
}

// ---------------------------------------------------------------------------
// Kernel 4: scatter (row,k) entries into per-expert lists, block-aggregated
// ---------------------------------------------------------------------------
__global__ __launch_bounds__(256) void build_list_kernel(
    const int* __restrict__ tki, int* __restrict__ cursor, int* __restrict__ list)
{
    __shared__ int lcnt[NEXP], lbase[NEXP];
    int tid = threadIdx.x;
    if (tid < NEXP) lcnt[tid] = 0;
    __syncthreads();
    int r = blockIdx.x * 256 + tid;
    int e0 = tki[r * 2], e1 = tki[r * 2 + 1];
    int p0 = atomicAdd(&lcnt[e0], 1);
    int p1 = atomicAdd(&lcnt[e1], 1);
    __syncthreads();
    if (tid < NEXP) lbase[tid] = atomicAdd(&cursor[tid], lcnt[tid]);
    __syncthreads();
    list[lbase[e0] + p0] = r * 2;
    list[lbase[e1] + p1] = r * 2 + 1;
}

// ---------------------------------------------------------------------------
// Kernel 5: grouped expert GEMM, 64 gathered rows x 256 cols per block.
// 4 waves: wave w covers cols [w*64, w*64+64). mfma_f32_16x16x32_bf16.
// A/B fragments loaded directly from global (L2-resident).
// ---------------------------------------------------------------------------
__global__ __launch_bounds__(256) void moe_gemm_kernel(
    const unsigned short* __restrict__ xb, const unsigned short* __restrict__ wb,
    const float* __restrict__ expb, const float* __restrict__ tkp,
    const int* __restrict__ list, const int* __restrict__ offs,
    const int* __restrict__ toff, float* __restrict__ out)
{
    int nblk = toff[NEXP];
    int b = blockIdx.x;
    if (b >= nblk) return;
    int e = 0;
    while (toff[e + 1] <= b) e++;
    int tile = b - toff[e];
    int m0 = offs[e] + tile * 64;
    int cnt = offs[e + 1] - offs[e];
    int nrows = min(64, cnt - tile * 64);

    __shared__ int   srow[64];
    __shared__ float sprob[64];
    int tid = threadIdx.x;
    if (tid < 64) {
        if (tid < nrows) {
            int ent = list[m0 + tid];
            srow[tid]  = ent >> 1;
            sprob[tid] = tkp[ent];
        } else { srow[tid] = -1; sprob[tid] = 0.f; }
    }
    __syncthreads();

    int wave = tid >> 6;
    int lane = tid & 63;
    int lr = lane & 15;   // A: row within 16-tile; B: col within 16-tile
    int kg = lane >> 4;   // k-group (8 contiguous k each)
    int n0 = wave * 64;

    f32x4 acc[4][4];
    #pragma unroll
    for (int mm = 0; mm < 4; mm++)
        #pragma unroll
        for (int nn = 0; nn < 4; nn++)
            acc[mm][nn] = (f32x4){0.f, 0.f, 0.f, 0.f};

    int arow[4];
    #pragma unroll
    for (int mm = 0; mm < 4; mm++) {
        int rr = srow[mm * 16 + lr];
        arow[mm] = (rr < 0) ? 0 : rr;
    }

    for (int kk = 0; kk < 8; kk++) {
        bf16x8 a[4], bb[4];
        #pragma unroll
        for (int mm = 0; mm < 4; mm++)
            a[mm] = *(const bf16x8*)(xb + (size_t)arow[mm] * D_INP + kk * 32 + kg * 8);
        #pragma unroll
        for (int nn = 0; nn < 4; nn++)
            bb[nn] = *(const bf16x8*)(wb + ((size_t)e * 256 + n0 + nn * 16 + lr) * D_INP + kk * 32 + kg * 8);
        #pragma unroll
        for (int mm = 0; mm < 4; mm++)
            #pragma unroll
            for (int nn = 0; nn < 4; nn++)
                acc[mm][nn] = __builtin_amdgcn_mfma_f32_16x16x32_bf16(a[mm], bb[nn], acc[mm][nn], 0, 0, 0);
    }

    // C/D layout: col = lane&15, row = (lane>>4)*4 + reg
    #pragma unroll
    for (int mm = 0; mm < 4; mm++) {
        #pragma unroll
        for (int j = 0; j < 4; j++) {
            int lrow = mm * 16 + kg * 4 + j;
            int rr = srow[lrow];
            float pp = sprob[lrow];
            if (rr >= 0) {
                #pragma unroll
                for (int nn = 0; nn < 4; nn++) {
                    int col = n0 + nn * 16 + lr;
                    float v = (acc[mm][nn][j] + expb[e * 256 + col]) * pp;
                    unsafeAtomicAdd(&out[(size_t)rr * D_OUTP + col], v);
                }
            }
        }
    }
}

// ---------------------------------------------------------------------------
extern "C" void kernel_launch(void* const* d_in, const int* in_sizes, int n_in,
                              void* d_out, int out_size, void* d_ws, size_t ws_size,
                              hipStream_t stream)
{
    const float* x   = (const float*)d_in[0];
    const float* noi = (const float*)d_in[1];
    const float* gw  = (const float*)d_in[2];
    const float* gb  = (const float*)d_in[3];
    const float* ew  = (const float*)d_in[4];
    const float* eb  = (const float*)d_in[5];
    float* out = (float*)d_out;

    char* p = (char*)d_ws;
    unsigned short* xb = (unsigned short*)p; p += (size_t)N_ROWS * D_INP * 2;
    unsigned short* wb = (unsigned short*)p; p += (size_t)NEXP * D_OUTP * D_INP * 2;
    float* tkp  = (float*)p; p += (size_t)N_ROWS * 2 * 4;
    int*   tki  = (int*)p;   p += (size_t)N_ROWS * 2 * 4;
    int*   list = (int*)p;   p += (size_t)N_ROWS * 2 * 4;
    float* esum = (float*)p; p += 32 * 4;
    int*   ecnt = (int*)p;   p += 32 * 4;
    int*   offs = (int*)p;   p += 33 * 4;
    int*   curs = (int*)p;   p += 33 * 4;
    int*   toff = (int*)p;   p += 33 * 4;

    hipMemsetAsync(esum, 0, 64 * 4, stream);                       // esum + ecnt
    hipMemsetAsync(d_out, 0, (size_t)N_ROWS * D_OUTP * 4, stream); // atomic accum target

    gate_kernel<<<N_ROWS / 8, 256, 0, stream>>>(x, noi, gw, gb, xb, tkp, tki, esum, ecnt);
    cast_w_kernel<<<(NEXP * D_OUTP * D_INP / 4) / 256, 256, 0, stream>>>(ew, wb);
    scan_kernel<<<1, 64, 0, stream>>>(esum, ecnt, offs, curs, toff, out + (size_t)N_ROWS * D_OUTP);
    build_list_kernel<<<N_ROWS / 256, 256, 0, stream>>>(tki, curs, list);
    moe_gemm_kernel<<<(N_ROWS * 2 / 64) + NEXP, 256, 0, stream>>>(xb, wb, eb, tkp, list, offs, toff, out);
}

// Round 2
// 235.874 us; speedup vs baseline: 1.4211x; 1.4211x over previous
//
#include <hip/hip_runtime.h>
#include <hip/hip_bf16.h>

#define N_ROWS 32768
#define D_INP  256
#define NEXP   32
#define D_OUTP 256

typedef __attribute__((ext_vector_type(4))) float f32x4;
typedef __attribute__((ext_vector_type(8))) short bf16x8;

__device__ inline unsigned short f2b(float f) {
    union { __hip_bfloat16 h; unsigned short u; } cv;
    cv.h = __float2bfloat16(f);
    return cv.u;
}

// ---------------------------------------------------------------------------
// Kernel 1 (v2): gate GEMM as register-blocked LDS-tiled fp32 GEMM.
// Grid = 256 blocks x 256 threads; each block owns 128 rows x 32 experts.
// Thread (e4 = tid&7, rq = tid>>3) computes rows {rq+32m} x experts {e4+8n}.
// LDS: gws[32][260] (whole gate weight, padded), xs[128][132] (K-half).
// Bank check: x-read bank = (4rq+4c+i)%32 over 8 rq-lanes -> all 32 banks,
// broadcast across e4 groups; gw-read symmetric. Conflict-free.
// Fused: bf16 cast of x emitted during staging.
// ---------------------------------------------------------------------------
__global__ __launch_bounds__(256) void gate_kernel(
    const float* __restrict__ x, const float* __restrict__ noise,
    const float* __restrict__ gw, const float* __restrict__ gb,
    unsigned short* __restrict__ xb, float* __restrict__ tkp,
    int* __restrict__ tki, float* __restrict__ esum, int* __restrict__ ecnt)
{
    __shared__ float gws[NEXP * 260];   // 33,280 B
    __shared__ float xs[128 * 132];     // 67,584 B
    __shared__ float lsum[NEXP];
    __shared__ int   lcnt[NEXP];

    int tid = threadIdx.x;
    int row0 = blockIdx.x * 128;

    // stage gw: 32*256 = 8192 floats = 2048 float4, 8 per thread
    #pragma unroll
    for (int it = 0; it < 8; ++it) {
        int q = it * 256 + tid;            // float4 index
        int e = q >> 6;                    // 64 float4 per expert row
        int k = (q & 63) * 4;
        float4 v = ((const float4*)gw)[q];
        *(float4*)&gws[e * 260 + k] = v;
    }
    if (tid < NEXP) { lsum[tid] = 0.f; lcnt[tid] = 0; }

    int e4 = tid & 7;
    int rq = tid >> 3;                     // 0..31

    float acc[4][4];
    #pragma unroll
    for (int m = 0; m < 4; m++)
        #pragma unroll
        for (int n = 0; n < 4; n++) acc[m][n] = 0.f;

    for (int h = 0; h < 2; ++h) {
        int ko = h * 128;
        __syncthreads();  // h=0: gw staged; h=1: previous compute done
        // stage xs: 128 rows x 128 k = 4096 float4, 16 per thread; fused bf16 cast
        #pragma unroll
        for (int it = 0; it < 16; ++it) {
            int idx = it * 256 + tid;
            int r = idx >> 5;              // 32 float4 per row-half
            int f = idx & 31;
            float4 v = *(const float4*)(x + (size_t)(row0 + r) * D_INP + ko + f * 4);
            *(float4*)&xs[r * 132 + f * 4] = v;
            unsigned short b[4] = { f2b(v.x), f2b(v.y), f2b(v.z), f2b(v.w) };
            *(ushort4*)(xb + (size_t)(row0 + r) * D_INP + ko + f * 4) = *(ushort4*)b;
        }
        __syncthreads();
        #pragma unroll 4
        for (int c = 0; c < 32; ++c) {
            float4 xv[4], wv[4];
            #pragma unroll
            for (int m = 0; m < 4; m++)
                xv[m] = *(float4*)&xs[(rq + 32 * m) * 132 + c * 4];
            #pragma unroll
            for (int n = 0; n < 4; n++)
                wv[n] = *(float4*)&gws[(e4 + 8 * n) * 260 + ko + c * 4];
            #pragma unroll
            for (int m = 0; m < 4; m++)
                #pragma unroll
                for (int n = 0; n < 4; n++)
                    acc[m][n] = fmaf(xv[m].x, wv[n].x,
                                fmaf(xv[m].y, wv[n].y,
                                fmaf(xv[m].z, wv[n].z,
                                fmaf(xv[m].w, wv[n].w, acc[m][n]))));
        }
    }

    // logits -> softmax -> top2, per row, across the 8-lane e4 group
    #pragma unroll
    for (int m = 0; m < 4; m++) {
        int R = row0 + rq + 32 * m;
        float l[4], p[4];
        #pragma unroll
        for (int n = 0; n < 4; n++) {
            int E = e4 + 8 * n;
            l[n] = acc[m][n] + gb[E] + 0.1f * noise[(size_t)R * NEXP + E];
        }
        float mx = fmaxf(fmaxf(l[0], l[1]), fmaxf(l[2], l[3]));
        #pragma unroll
        for (int s = 1; s < 8; s <<= 1) mx = fmaxf(mx, __shfl_xor(mx, s));
        float sum = 0.f;
        #pragma unroll
        for (int n = 0; n < 4; n++) { p[n] = expf(l[n] - mx); sum += p[n]; }
        #pragma unroll
        for (int s = 1; s < 8; s <<= 1) sum += __shfl_xor(sum, s);
        float inv = 1.f / sum;
        #pragma unroll
        for (int n = 0; n < 4; n++) p[n] *= inv;

        // top-1 (ties -> lower expert index; n ascending keeps lower index)
        float bp = p[0]; int bi = e4;
        #pragma unroll
        for (int n = 1; n < 4; n++) if (p[n] > bp) { bp = p[n]; bi = e4 + 8 * n; }
        #pragma unroll
        for (int s = 1; s < 8; s <<= 1) {
            float op = __shfl_xor(bp, s); int oi = __shfl_xor(bi, s);
            if (op > bp || (op == bp && oi < bi)) { bp = op; bi = oi; }
        }
        // top-2
        float bp2 = -1.f; int bi2 = 0;
        #pragma unroll
        for (int n = 0; n < 4; n++) {
            int E = e4 + 8 * n;
            float q = (E == bi) ? -1.f : p[n];
            if (q > bp2 || (q == bp2 && E < bi2)) { bp2 = q; bi2 = E; }
        }
        #pragma unroll
        for (int s = 1; s < 8; s <<= 1) {
            float op = __shfl_xor(bp2, s); int oi = __shfl_xor(bi2, s);
            if (op > bp2 || (op == bp2 && oi < bi2)) { bp2 = op; bi2 = oi; }
        }
        if (e4 == 0) {
            tkp[R * 2] = bp;  tkp[R * 2 + 1] = bp2;
            tki[R * 2] = bi;  tki[R * 2 + 1] = bi2;
            atomicAdd(&lcnt[bi], 1); atomicAdd(&lcnt[bi2], 1);
        }
        #pragma unroll
        for (int n = 0; n < 4; n++) atomicAdd(&lsum[e4 + 8 * n], p[n]);
    }
    __syncthreads();
    if (tid < NEXP) {
        unsafeAtomicAdd(&esum[tid], lsum[tid]);
        atomicAdd(&ecnt[tid], lcnt[tid]);
    }
}

// ---------------------------------------------------------------------------
// Kernel 2: experts_w fp32 -> bf16
// ---------------------------------------------------------------------------
__global__ __launch_bounds__(256) void cast_w_kernel(
    const float* __restrict__ w, unsigned short* __restrict__ wb)
{
    size_t i = (size_t)blockIdx.x * 256 + threadIdx.x; // one float4 each
    float4 v = ((const float4*)w)[i];
    unsigned short t[4] = { f2b(v.x), f2b(v.y), f2b(v.z), f2b(v.w) };
    ((ushort4*)wb)[i] = *(ushort4*)t;
}

// ---------------------------------------------------------------------------
// Kernel 3: prefix sums (row offsets + tile offsets) and load-balance loss
// ---------------------------------------------------------------------------
__global__ void scan_kernel(const float* __restrict__ esum, const int* __restrict__ ecnt,
                            int* __restrict__ offs, int* __restrict__ cursor,
                            int* __restrict__ toff, float* __restrict__ loss_out)
{
    int t = threadIdx.x;
    if (t == 0) {
        int acc = 0, ta = 0;
        for (int e = 0; e < NEXP; e++) {
            offs[e] = acc; cursor[e] = acc; toff[e] = ta;
            int c = ecnt[e];
            acc += c; ta += (c + 63) >> 6;
        }
        offs[NEXP] = acc; toff[NEXP] = ta;
    }
    if (t < 32) {
        float d = esum[t] * (1.f / N_ROWS) - (1.f / NEXP);
        float v = d * d;
        #pragma unroll
        for (int s = 16; s > 0; s >>= 1) v += __shfl_xor(v, s, 32);
        if (t == 0) *loss_out = v;  // mean((m-1/E)^2)*E == sum
    }
}

// ---------------------------------------------------------------------------
// Kernel 4: scatter (row,k) entries into per-expert lists, block-aggregated
// ---------------------------------------------------------------------------
__global__ __launch_bounds__(256) void build_list_kernel(
    const int* __restrict__ tki, int* __restrict__ cursor, int* __restrict__ list)
{
    __shared__ int lcnt[NEXP], lbase[NEXP];
    int tid = threadIdx.x;
    if (tid < NEXP) lcnt[tid] = 0;
    __syncthreads();
    int r = blockIdx.x * 256 + tid;
    int e0 = tki[r * 2], e1 = tki[r * 2 + 1];
    int p0 = atomicAdd(&lcnt[e0], 1);
    int p1 = atomicAdd(&lcnt[e1], 1);
    __syncthreads();
    if (tid < NEXP) lbase[tid] = atomicAdd(&cursor[tid], lcnt[tid]);
    __syncthreads();
    list[lbase[e0] + p0] = r * 2;
    list[lbase[e1] + p1] = r * 2 + 1;
}

// ---------------------------------------------------------------------------
// Kernel 5: grouped expert GEMM, 64 gathered rows x 256 cols per block.
// 4 waves: wave w covers cols [w*64, w*64+64). mfma_f32_16x16x32_bf16.
// A/B fragments loaded directly from global (L2-resident).
// ---------------------------------------------------------------------------
__global__ __launch_bounds__(256) void moe_gemm_kernel(
    const unsigned short* __restrict__ xb, const unsigned short* __restrict__ wb,
    const float* __restrict__ expb, const float* __restrict__ tkp,
    const int* __restrict__ list, const int* __restrict__ offs,
    const int* __restrict__ toff, float* __restrict__ out)
{
    int nblk = toff[NEXP];
    int b = blockIdx.x;
    if (b >= nblk) return;
    int e = 0;
    while (toff[e + 1] <= b) e++;
    int tile = b - toff[e];
    int m0 = offs[e] + tile * 64;
    int cnt = offs[e + 1] - offs[e];
    int nrows = min(64, cnt - tile * 64);

    __shared__ int   srow[64];
    __shared__ float sprob[64];
    int tid = threadIdx.x;
    if (tid < 64) {
        if (tid < nrows) {
            int ent = list[m0 + tid];
            srow[tid]  = ent >> 1;
            sprob[tid] = tkp[ent];
        } else { srow[tid] = -1; sprob[tid] = 0.f; }
    }
    __syncthreads();

    int wave = tid >> 6;
    int lane = tid & 63;
    int lr = lane & 15;   // A: row within 16-tile; B: col within 16-tile
    int kg = lane >> 4;   // k-group (8 contiguous k each)
    int n0 = wave * 64;

    f32x4 acc[4][4];
    #pragma unroll
    for (int mm = 0; mm < 4; mm++)
        #pragma unroll
        for (int nn = 0; nn < 4; nn++)
            acc[mm][nn] = (f32x4){0.f, 0.f, 0.f, 0.f};

    int arow[4];
    #pragma unroll
    for (int mm = 0; mm < 4; mm++) {
        int rr = srow[mm * 16 + lr];
        arow[mm] = (rr < 0) ? 0 : rr;
    }

    for (int kk = 0; kk < 8; kk++) {
        bf16x8 a[4], bb[4];
        #pragma unroll
        for (int mm = 0; mm < 4; mm++)
            a[mm] = *(const bf16x8*)(xb + (size_t)arow[mm] * D_INP + kk * 32 + kg * 8);
        #pragma unroll
        for (int nn = 0; nn < 4; nn++)
            bb[nn] = *(const bf16x8*)(wb + ((size_t)e * 256 + n0 + nn * 16 + lr) * D_INP + kk * 32 + kg * 8);
        #pragma unroll
        for (int mm = 0; mm < 4; mm++)
            #pragma unroll
            for (int nn = 0; nn < 4; nn++)
                acc[mm][nn] = __builtin_amdgcn_mfma_f32_16x16x32_bf16(a[mm], bb[nn], acc[mm][nn], 0, 0, 0);
    }

    // C/D layout: col = lane&15, row = (lane>>4)*4 + reg
    #pragma unroll
    for (int mm = 0; mm < 4; mm++) {
        #pragma unroll
        for (int j = 0; j < 4; j++) {
            int lrow = mm * 16 + kg * 4 + j;
            int rr = srow[lrow];
            float pp = sprob[lrow];
            if (rr >= 0) {
                #pragma unroll
                for (int nn = 0; nn < 4; nn++) {
                    int col = n0 + nn * 16 + lr;
                    float v = (acc[mm][nn][j] + expb[e * 256 + col]) * pp;
                    unsafeAtomicAdd(&out[(size_t)rr * D_OUTP + col], v);
                }
            }
        }
    }
}

// ---------------------------------------------------------------------------
extern "C" void kernel_launch(void* const* d_in, const int* in_sizes, int n_in,
                              void* d_out, int out_size, void* d_ws, size_t ws_size,
                              hipStream_t stream)
{
    const float* x   = (const float*)d_in[0];
    const float* noi = (const float*)d_in[1];
    const float* gw  = (const float*)d_in[2];
    const float* gb  = (const float*)d_in[3];
    const float* ew  = (const float*)d_in[4];
    const float* eb  = (const float*)d_in[5];
    float* out = (float*)d_out;

    char* p = (char*)d_ws;
    unsigned short* xb = (unsigned short*)p; p += (size_t)N_ROWS * D_INP * 2;
    unsigned short* wb = (unsigned short*)p; p += (size_t)NEXP * D_OUTP * D_INP * 2;
    float* tkp  = (float*)p; p += (size_t)N_ROWS * 2 * 4;
    int*   tki  = (int*)p;   p += (size_t)N_ROWS * 2 * 4;
    int*   list = (int*)p;   p += (size_t)N_ROWS * 2 * 4;
    float* esum = (float*)p; p += 32 * 4;
    int*   ecnt = (int*)p;   p += 32 * 4;
    int*   offs = (int*)p;   p += 33 * 4;
    int*   curs = (int*)p;   p += 33 * 4;
    int*   toff = (int*)p;   p += 33 * 4;

    hipMemsetAsync(esum, 0, 64 * 4, stream);                       // esum + ecnt
    hipMemsetAsync(d_out, 0, (size_t)N_ROWS * D_OUTP * 4, stream); // atomic accum target

    gate_kernel<<<N_ROWS / 128, 256, 0, stream>>>(x, noi, gw, gb, xb, tkp, tki, esum, ecnt);
    cast_w_kernel<<<(NEXP * D_OUTP * D_INP / 4) / 256, 256, 0, stream>>>(ew, wb);
    scan_kernel<<<1, 64, 0, stream>>>(esum, ecnt, offs, curs, toff, out + (size_t)N_ROWS * D_OUTP);
    build_list_kernel<<<N_ROWS / 256, 256, 0, stream>>>(tki, curs, list);
    moe_gemm_kernel<<<(N_ROWS * 2 / 64) + NEXP, 256, 0, stream>>>(xb, wb, eb, tkp, list, offs, toff, out);
}

// Round 3
// 180.177 us; speedup vs baseline: 1.8604x; 1.3091x over previous
//
#include <hip/hip_runtime.h>
#include <hip/hip_bf16.h>

#define N_ROWS 32768
#define D_INP  256
#define NEXP   32
#define D_OUTP 256

typedef __attribute__((ext_vector_type(4))) float f32x4;
typedef __attribute__((ext_vector_type(8))) short bf16x8;

__device__ inline unsigned short f2b(float f) {
    union { __hip_bfloat16 h; unsigned short u; } cv;
    cv.h = __float2bfloat16(f);
    return cv.u;
}

// ---------------------------------------------------------------------------
// Kernel 1: gate GEMM (fp32, LDS-tiled, register-blocked) + softmax + top-2
// + per-expert stats; fused bf16 cast of x. 128 rows/block, grid 256.
// ---------------------------------------------------------------------------
__global__ __launch_bounds__(256) void gate_kernel(
    const float* __restrict__ x, const float* __restrict__ noise,
    const float* __restrict__ gw, const float* __restrict__ gb,
    unsigned short* __restrict__ xb, float* __restrict__ tkp,
    int* __restrict__ tki, float* __restrict__ esum, int* __restrict__ ecnt)
{
    __shared__ float gws[NEXP * 260];
    __shared__ float xs[128 * 132];
    __shared__ float lsum[NEXP];
    __shared__ int   lcnt[NEXP];

    int tid = threadIdx.x;
    int row0 = blockIdx.x * 128;

    #pragma unroll
    for (int it = 0; it < 8; ++it) {
        int q = it * 256 + tid;
        int e = q >> 6;
        int k = (q & 63) * 4;
        float4 v = ((const float4*)gw)[q];
        *(float4*)&gws[e * 260 + k] = v;
    }
    if (tid < NEXP) { lsum[tid] = 0.f; lcnt[tid] = 0; }

    int e4 = tid & 7;
    int rq = tid >> 3;

    float acc[4][4];
    #pragma unroll
    for (int m = 0; m < 4; m++)
        #pragma unroll
        for (int n = 0; n < 4; n++) acc[m][n] = 0.f;

    for (int h = 0; h < 2; ++h) {
        int ko = h * 128;
        __syncthreads();
        #pragma unroll
        for (int it = 0; it < 16; ++it) {
            int idx = it * 256 + tid;
            int r = idx >> 5;
            int f = idx & 31;
            float4 v = *(const float4*)(x + (size_t)(row0 + r) * D_INP + ko + f * 4);
            *(float4*)&xs[r * 132 + f * 4] = v;
            unsigned short b[4] = { f2b(v.x), f2b(v.y), f2b(v.z), f2b(v.w) };
            *(ushort4*)(xb + (size_t)(row0 + r) * D_INP + ko + f * 4) = *(ushort4*)b;
        }
        __syncthreads();
        #pragma unroll 4
        for (int c = 0; c < 32; ++c) {
            float4 xv[4], wv[4];
            #pragma unroll
            for (int m = 0; m < 4; m++)
                xv[m] = *(float4*)&xs[(rq + 32 * m) * 132 + c * 4];
            #pragma unroll
            for (int n = 0; n < 4; n++)
                wv[n] = *(float4*)&gws[(e4 + 8 * n) * 260 + ko + c * 4];
            #pragma unroll
            for (int m = 0; m < 4; m++)
                #pragma unroll
                for (int n = 0; n < 4; n++)
                    acc[m][n] = fmaf(xv[m].x, wv[n].x,
                                fmaf(xv[m].y, wv[n].y,
                                fmaf(xv[m].z, wv[n].z,
                                fmaf(xv[m].w, wv[n].w, acc[m][n]))));
        }
    }

    #pragma unroll
    for (int m = 0; m < 4; m++) {
        int R = row0 + rq + 32 * m;
        float l[4], p[4];
        #pragma unroll
        for (int n = 0; n < 4; n++) {
            int E = e4 + 8 * n;
            l[n] = acc[m][n] + gb[E] + 0.1f * noise[(size_t)R * NEXP + E];
        }
        float mx = fmaxf(fmaxf(l[0], l[1]), fmaxf(l[2], l[3]));
        #pragma unroll
        for (int s = 1; s < 8; s <<= 1) mx = fmaxf(mx, __shfl_xor(mx, s));
        float sum = 0.f;
        #pragma unroll
        for (int n = 0; n < 4; n++) { p[n] = expf(l[n] - mx); sum += p[n]; }
        #pragma unroll
        for (int s = 1; s < 8; s <<= 1) sum += __shfl_xor(sum, s);
        float inv = 1.f / sum;
        #pragma unroll
        for (int n = 0; n < 4; n++) p[n] *= inv;

        float bp = p[0]; int bi = e4;
        #pragma unroll
        for (int n = 1; n < 4; n++) if (p[n] > bp) { bp = p[n]; bi = e4 + 8 * n; }
        #pragma unroll
        for (int s = 1; s < 8; s <<= 1) {
            float op = __shfl_xor(bp, s); int oi = __shfl_xor(bi, s);
            if (op > bp || (op == bp && oi < bi)) { bp = op; bi = oi; }
        }
        float bp2 = -1.f; int bi2 = 0;
        #pragma unroll
        for (int n = 0; n < 4; n++) {
            int E = e4 + 8 * n;
            float q = (E == bi) ? -1.f : p[n];
            if (q > bp2 || (q == bp2 && E < bi2)) { bp2 = q; bi2 = E; }
        }
        #pragma unroll
        for (int s = 1; s < 8; s <<= 1) {
            float op = __shfl_xor(bp2, s); int oi = __shfl_xor(bi2, s);
            if (op > bp2 || (op == bp2 && oi < bi2)) { bp2 = op; bi2 = oi; }
        }
        if (e4 == 0) {
            tkp[R * 2] = bp;  tkp[R * 2 + 1] = bp2;
            tki[R * 2] = bi;  tki[R * 2 + 1] = bi2;
            atomicAdd(&lcnt[bi], 1); atomicAdd(&lcnt[bi2], 1);
        }
        #pragma unroll
        for (int n = 0; n < 4; n++) atomicAdd(&lsum[e4 + 8 * n], p[n]);
    }
    __syncthreads();
    if (tid < NEXP) {
        unsafeAtomicAdd(&esum[tid], lsum[tid]);
        atomicAdd(&ecnt[tid], lcnt[tid]);
    }
}

// ---------------------------------------------------------------------------
// Kernel 2: experts_w fp32 -> bf16
// ---------------------------------------------------------------------------
__global__ __launch_bounds__(256) void cast_w_kernel(
    const float* __restrict__ w, unsigned short* __restrict__ wb)
{
    size_t i = (size_t)blockIdx.x * 256 + threadIdx.x;
    float4 v = ((const float4*)w)[i];
    unsigned short t[4] = { f2b(v.x), f2b(v.y), f2b(v.z), f2b(v.w) };
    ((ushort4*)wb)[i] = *(ushort4*)t;
}

// ---------------------------------------------------------------------------
// Kernel 3: prefix sums + load-balance loss
// ---------------------------------------------------------------------------
__global__ void scan_kernel(const float* __restrict__ esum, const int* __restrict__ ecnt,
                            int* __restrict__ offs, int* __restrict__ cursor,
                            int* __restrict__ toff, float* __restrict__ loss_out)
{
    int t = threadIdx.x;
    if (t == 0) {
        int acc = 0, ta = 0;
        for (int e = 0; e < NEXP; e++) {
            offs[e] = acc; cursor[e] = acc; toff[e] = ta;
            int c = ecnt[e];
            acc += c; ta += (c + 63) >> 6;
        }
        offs[NEXP] = acc; toff[NEXP] = ta;
    }
    if (t < 32) {
        float d = esum[t] * (1.f / N_ROWS) - (1.f / NEXP);
        float v = d * d;
        #pragma unroll
        for (int s = 16; s > 0; s >>= 1) v += __shfl_xor(v, s, 32);
        if (t == 0) *loss_out = v;
    }
}

// ---------------------------------------------------------------------------
// Kernel 4: scatter (row,slot) entries into per-expert lists
// ---------------------------------------------------------------------------
__global__ __launch_bounds__(256) void build_list_kernel(
    const int* __restrict__ tki, int* __restrict__ cursor, int* __restrict__ list)
{
    __shared__ int lcnt[NEXP], lbase[NEXP];
    int tid = threadIdx.x;
    if (tid < NEXP) lcnt[tid] = 0;
    __syncthreads();
    int r = blockIdx.x * 256 + tid;
    int e0 = tki[r * 2], e1 = tki[r * 2 + 1];
    int p0 = atomicAdd(&lcnt[e0], 1);
    int p1 = atomicAdd(&lcnt[e1], 1);
    __syncthreads();
    if (tid < NEXP) lbase[tid] = atomicAdd(&cursor[tid], lcnt[tid]);
    __syncthreads();
    list[lbase[e0] + p0] = r * 2;
    list[lbase[e1] + p1] = r * 2 + 1;
}

// ---------------------------------------------------------------------------
// Kernel 5: grouped expert GEMM. 64 gathered rows x 256 cols per block.
// A-tile staged once into LDS (16B-chunk XOR swizzle, conflict-free reads).
// Epilogue: NO atomics — slot0 (top-1) stores straight to out (unique writer
// per row), slot1 stores to y1; combine_kernel adds them.
// ---------------------------------------------------------------------------
__global__ __launch_bounds__(256) void moe_gemm_kernel(
    const unsigned short* __restrict__ xb, const unsigned short* __restrict__ wb,
    const float* __restrict__ expb, const float* __restrict__ tkp,
    const int* __restrict__ list, const int* __restrict__ offs,
    const int* __restrict__ toff, float* __restrict__ out, float* __restrict__ y1)
{
    int nblk = toff[NEXP];
    int b = blockIdx.x;
    if (b >= nblk) return;
    int e = 0;
    while (toff[e + 1] <= b) e++;
    int tile = b - toff[e];
    int m0 = offs[e] + tile * 64;
    int cnt = offs[e + 1] - offs[e];
    int nrows = min(64, cnt - tile * 64);

    __shared__ unsigned short xa[64 * 256];   // 32 KB swizzled A tile
    __shared__ int   srow[64];
    __shared__ int   sslot[64];
    __shared__ float sprob[64];
    int tid = threadIdx.x;
    if (tid < 64) {
        if (tid < nrows) {
            int ent = list[m0 + tid];
            srow[tid]  = ent >> 1;
            sslot[tid] = ent & 1;
            sprob[tid] = tkp[ent];
        } else { srow[tid] = -1; sslot[tid] = 0; sprob[tid] = 0.f; }
    }
    __syncthreads();

    // stage A: thread t -> LDS row t>>2, chunks (t&3) + 4*i (16B chunks, 32/row)
    {
        int r_ = tid >> 2;
        int gr = srow[r_];
        const uint4* src = (const uint4*)(xb + (size_t)(gr < 0 ? 0 : gr) * D_INP);
        uint4* dst = (uint4*)xa;
        int swz = r_ & 7;
        #pragma unroll
        for (int i = 0; i < 8; ++i) {
            int c = (tid & 3) + 4 * i;
            dst[r_ * 32 + (c ^ swz)] = src[c];
        }
    }
    __syncthreads();

    int wave = tid >> 6;
    int lane = tid & 63;
    int lr = lane & 15;
    int kg = lane >> 4;
    int n0 = wave * 64;
    int aswz = lr & 7;

    f32x4 acc[4][4];
    #pragma unroll
    for (int mm = 0; mm < 4; mm++)
        #pragma unroll
        for (int nn = 0; nn < 4; nn++)
            acc[mm][nn] = (f32x4){0.f, 0.f, 0.f, 0.f};

    for (int kk = 0; kk < 8; kk++) {
        int chunk = kk * 4 + kg;
        int aoff = (chunk ^ aswz) * 8;
        bf16x8 a[4], bb[4];
        #pragma unroll
        for (int mm = 0; mm < 4; mm++)
            a[mm] = *(const bf16x8*)&xa[(mm * 16 + lr) * 256 + aoff];
        #pragma unroll
        for (int nn = 0; nn < 4; nn++)
            bb[nn] = *(const bf16x8*)(wb + ((size_t)e * 256 + n0 + nn * 16 + lr) * D_INP + kk * 32 + kg * 8);
        #pragma unroll
        for (int mm = 0; mm < 4; mm++)
            #pragma unroll
            for (int nn = 0; nn < 4; nn++)
                acc[mm][nn] = __builtin_amdgcn_mfma_f32_16x16x32_bf16(a[mm], bb[nn], acc[mm][nn], 0, 0, 0);
    }

    // C/D layout: col = lane&15, row = (lane>>4)*4 + reg
    #pragma unroll
    for (int mm = 0; mm < 4; mm++) {
        #pragma unroll
        for (int j = 0; j < 4; j++) {
            int lrow = mm * 16 + kg * 4 + j;
            int rr = srow[lrow];
            if (rr >= 0) {
                float pp = sprob[lrow];
                float* dst = sslot[lrow] ? y1 : out;
                #pragma unroll
                for (int nn = 0; nn < 4; nn++) {
                    int col = n0 + nn * 16 + lr;
                    dst[(size_t)rr * D_OUTP + col] = (acc[mm][nn][j] + expb[e * 256 + col]) * pp;
                }
            }
        }
    }
}

// ---------------------------------------------------------------------------
// Kernel 6: out += y1 (pure streaming)
// ---------------------------------------------------------------------------
__global__ __launch_bounds__(256) void combine_kernel(
    const float* __restrict__ y1, float* __restrict__ out)
{
    size_t i = ((size_t)blockIdx.x * 256 + threadIdx.x) * 4;
    float4 a = *(const float4*)(out + i);
    float4 b = *(const float4*)(y1 + i);
    a.x += b.x; a.y += b.y; a.z += b.z; a.w += b.w;
    *(float4*)(out + i) = a;
}

// ---------------------------------------------------------------------------
extern "C" void kernel_launch(void* const* d_in, const int* in_sizes, int n_in,
                              void* d_out, int out_size, void* d_ws, size_t ws_size,
                              hipStream_t stream)
{
    const float* x   = (const float*)d_in[0];
    const float* noi = (const float*)d_in[1];
    const float* gw  = (const float*)d_in[2];
    const float* gb  = (const float*)d_in[3];
    const float* ew  = (const float*)d_in[4];
    const float* eb  = (const float*)d_in[5];
    float* out = (float*)d_out;

    char* p = (char*)d_ws;
    unsigned short* xb = (unsigned short*)p; p += (size_t)N_ROWS * D_INP * 2;
    unsigned short* wb = (unsigned short*)p; p += (size_t)NEXP * D_OUTP * D_INP * 2;
    float* y1   = (float*)p; p += (size_t)N_ROWS * D_OUTP * 4;
    float* tkp  = (float*)p; p += (size_t)N_ROWS * 2 * 4;
    int*   tki  = (int*)p;   p += (size_t)N_ROWS * 2 * 4;
    int*   list = (int*)p;   p += (size_t)N_ROWS * 2 * 4;
    float* esum = (float*)p; p += 32 * 4;
    int*   ecnt = (int*)p;   p += 32 * 4;
    int*   offs = (int*)p;   p += 33 * 4;
    int*   curs = (int*)p;   p += 33 * 4;
    int*   toff = (int*)p;   p += 33 * 4;

    hipMemsetAsync(esum, 0, 64 * 4, stream);  // esum + ecnt

    gate_kernel<<<N_ROWS / 128, 256, 0, stream>>>(x, noi, gw, gb, xb, tkp, tki, esum, ecnt);
    cast_w_kernel<<<(NEXP * D_OUTP * D_INP / 4) / 256, 256, 0, stream>>>(ew, wb);
    scan_kernel<<<1, 64, 0, stream>>>(esum, ecnt, offs, curs, toff, out + (size_t)N_ROWS * D_OUTP);
    build_list_kernel<<<N_ROWS / 256, 256, 0, stream>>>(tki, curs, list);
    moe_gemm_kernel<<<(N_ROWS * 2 / 64) + NEXP, 256, 0, stream>>>(xb, wb, eb, tkp, list, offs, toff, out, y1);
    combine_kernel<<<N_ROWS * D_OUTP / 4 / 256, 256, 0, stream>>>(y1, out);
}

// Round 5
// 179.118 us; speedup vs baseline: 1.8715x; 1.0059x over previous
//
#include <hip/hip_runtime.h>
#include <hip/hip_bf16.h>

#define N_ROWS 32768
#define D_INP  256
#define NEXP   32
#define D_OUTP 256
#define TROWS  32
#define NTILES 2080   // max tiles: 65536/32 + 32

typedef __attribute__((ext_vector_type(4))) float f32x4;
typedef __attribute__((ext_vector_type(8))) short bf16x8;

__device__ inline unsigned short f2b(float f) {
    union { __hip_bfloat16 h; unsigned short u; } cv;
    cv.h = __float2bfloat16(f);
    return cv.u;
}
__device__ inline float b2f(unsigned short u) {
    union { unsigned v; float f; } c; c.v = ((unsigned)u) << 16; return c.f;
}

// ---------------------------------------------------------------------------
// Kernel 1: gate GEMM (fp32 LDS-tiled) + softmax + top-2 + stats
// + fused bf16 cast of x AND of experts_w (each block casts 1/256th of ew).
// ---------------------------------------------------------------------------
__global__ __launch_bounds__(256) void gate_kernel(
    const float* __restrict__ x, const float* __restrict__ noise,
    const float* __restrict__ gw, const float* __restrict__ gb,
    const float* __restrict__ ew, unsigned short* __restrict__ wbh,
    unsigned short* __restrict__ xb, float* __restrict__ tkp,
    int* __restrict__ tki, float* __restrict__ esum, int* __restrict__ ecnt)
{
    __shared__ float gws[NEXP * 260];
    __shared__ float xs[128 * 132];
    __shared__ float lsum[NEXP];
    __shared__ int   lcnt[NEXP];

    int tid = threadIdx.x;
    int row0 = blockIdx.x * 128;

    #pragma unroll
    for (int it = 0; it < 8; ++it) {
        int q = it * 256 + tid;
        int e = q >> 6;
        int k = (q & 63) * 4;
        float4 v = ((const float4*)gw)[q];
        *(float4*)&gws[e * 260 + k] = v;
    }
    if (tid < NEXP) { lsum[tid] = 0.f; lcnt[tid] = 0; }

    int e4 = tid & 7;
    int rq = tid >> 3;

    float acc[4][4];
    #pragma unroll
    for (int m = 0; m < 4; m++)
        #pragma unroll
        for (int n = 0; n < 4; n++) acc[m][n] = 0.f;

    for (int h = 0; h < 2; ++h) {
        int ko = h * 128;
        __syncthreads();
        #pragma unroll
        for (int it = 0; it < 16; ++it) {
            int idx = it * 256 + tid;
            int r = idx >> 5;
            int f = idx & 31;
            float4 v = *(const float4*)(x + (size_t)(row0 + r) * D_INP + ko + f * 4);
            *(float4*)&xs[r * 132 + f * 4] = v;
            unsigned short b[4] = { f2b(v.x), f2b(v.y), f2b(v.z), f2b(v.w) };
            *(ushort4*)(xb + (size_t)(row0 + r) * D_INP + ko + f * 4) = *(ushort4*)b;
        }
        __syncthreads();
        #pragma unroll 4
        for (int c = 0; c < 32; ++c) {
            float4 xv[4], wv[4];
            #pragma unroll
            for (int m = 0; m < 4; m++)
                xv[m] = *(float4*)&xs[(rq + 32 * m) * 132 + c * 4];
            #pragma unroll
            for (int n = 0; n < 4; n++)
                wv[n] = *(float4*)&gws[(e4 + 8 * n) * 260 + ko + c * 4];
            #pragma unroll
            for (int m = 0; m < 4; m++)
                #pragma unroll
                for (int n = 0; n < 4; n++)
                    acc[m][n] = fmaf(xv[m].x, wv[n].x,
                                fmaf(xv[m].y, wv[n].y,
                                fmaf(xv[m].z, wv[n].z,
                                fmaf(xv[m].w, wv[n].w, acc[m][n]))));
        }
    }

    #pragma unroll
    for (int m = 0; m < 4; m++) {
        int R = row0 + rq + 32 * m;
        float l[4], p[4];
        #pragma unroll
        for (int n = 0; n < 4; n++) {
            int E = e4 + 8 * n;
            l[n] = acc[m][n] + gb[E] + 0.1f * noise[(size_t)R * NEXP + E];
        }
        float mx = fmaxf(fmaxf(l[0], l[1]), fmaxf(l[2], l[3]));
        #pragma unroll
        for (int s = 1; s < 8; s <<= 1) mx = fmaxf(mx, __shfl_xor(mx, s));
        float sum = 0.f;
        #pragma unroll
        for (int n = 0; n < 4; n++) { p[n] = expf(l[n] - mx); sum += p[n]; }
        #pragma unroll
        for (int s = 1; s < 8; s <<= 1) sum += __shfl_xor(sum, s);
        float inv = 1.f / sum;
        #pragma unroll
        for (int n = 0; n < 4; n++) p[n] *= inv;

        float bp = p[0]; int bi = e4;
        #pragma unroll
        for (int n = 1; n < 4; n++) if (p[n] > bp) { bp = p[n]; bi = e4 + 8 * n; }
        #pragma unroll
        for (int s = 1; s < 8; s <<= 1) {
            float op = __shfl_xor(bp, s); int oi = __shfl_xor(bi, s);
            if (op > bp || (op == bp && oi < bi)) { bp = op; bi = oi; }
        }
        float bp2 = -1.f; int bi2 = 0;
        #pragma unroll
        for (int n = 0; n < 4; n++) {
            int E = e4 + 8 * n;
            float q = (E == bi) ? -1.f : p[n];
            if (q > bp2 || (q == bp2 && E < bi2)) { bp2 = q; bi2 = E; }
        }
        #pragma unroll
        for (int s = 1; s < 8; s <<= 1) {
            float op = __shfl_xor(bp2, s); int oi = __shfl_xor(bi2, s);
            if (op > bp2 || (op == bp2 && oi < bi2)) { bp2 = op; bi2 = oi; }
        }
        if (e4 == 0) {
            tkp[R * 2] = bp;  tkp[R * 2 + 1] = bp2;
            tki[R * 2] = bi;  tki[R * 2 + 1] = bi2;
            atomicAdd(&lcnt[bi], 1); atomicAdd(&lcnt[bi2], 1);
        }
        #pragma unroll
        for (int n = 0; n < 4; n++) atomicAdd(&lsum[e4 + 8 * n], p[n]);
    }

    // fused experts_w cast: this block handles float4s [blockIdx*2048, +2048)
    {
        size_t base = (size_t)blockIdx.x * 2048;
        #pragma unroll
        for (int it = 0; it < 8; ++it) {
            size_t q = base + it * 256 + tid;
            float4 v = ((const float4*)ew)[q];
            unsigned short t4[4] = { f2b(v.x), f2b(v.y), f2b(v.z), f2b(v.w) };
            ((ushort4*)wbh)[q] = *(ushort4*)t4;
        }
    }

    __syncthreads();
    if (tid < NEXP) {
        unsafeAtomicAdd(&esum[tid], lsum[tid]);
        atomicAdd(&ecnt[tid], lcnt[tid]);
    }
}

// ---------------------------------------------------------------------------
// Kernel 2: parallel scan + loss + block->(expert,tile) table
// ---------------------------------------------------------------------------
__global__ __launch_bounds__(256) void scan_kernel(
    const float* __restrict__ esum, const int* __restrict__ ecnt,
    int* __restrict__ offs, int* __restrict__ cursor,
    int* __restrict__ tile_tab, float* __restrict__ loss_out)
{
    __shared__ int s_offs[NEXP + 1], s_toff[NEXP + 1];
    int t = threadIdx.x;
    if (t < 32) {
        int c = ecnt[t];
        int ic = c, itc = (c + TROWS - 1) / TROWS;
        #pragma unroll
        for (int s = 1; s < 32; s <<= 1) {
            int a = __shfl_up(ic, s, 32);  if (t >= s) ic += a;
            int b = __shfl_up(itc, s, 32); if (t >= s) itc += b;
        }
        s_offs[t + 1] = ic; s_toff[t + 1] = itc;
        if (t == 0) { s_offs[0] = 0; s_toff[0] = 0; }
    }
    __syncthreads();
    if (t < 32) {
        offs[t] = s_offs[t]; cursor[t] = s_offs[t];
        if (t == 0) offs[NEXP] = s_offs[NEXP];
        float d = esum[t] * (1.f / N_ROWS) - (1.f / NEXP);
        float v = d * d;
        #pragma unroll
        for (int s = 16; s > 0; s >>= 1) v += __shfl_xor(v, s, 32);
        if (t == 0) *loss_out = v;
    }
    int ntile = s_toff[NEXP];
    for (int b = t; b < NTILES; b += 256) {
        if (b < ntile) {
            int e = 0;
            #pragma unroll
            for (int s = 16; s; s >>= 1)
                if (e + s <= 31 && s_toff[e + s] <= b) e += s;
            int tile = b - s_toff[e];
            int m0 = s_offs[e] + tile * TROWS;
            int nr = min(TROWS, s_offs[e + 1] - m0);
            tile_tab[b * 2]     = e | (nr << 8);
            tile_tab[b * 2 + 1] = m0;
        } else {
            tile_tab[b * 2] = 0; tile_tab[b * 2 + 1] = 0;
        }
    }
}

// ---------------------------------------------------------------------------
// Kernel 3: scatter (row,slot) entries into per-expert lists
// ---------------------------------------------------------------------------
__global__ __launch_bounds__(256) void build_list_kernel(
    const int* __restrict__ tki, int* __restrict__ cursor, int* __restrict__ list)
{
    __shared__ int lcnt[NEXP], lbase[NEXP];
    int tid = threadIdx.x;
    if (tid < NEXP) lcnt[tid] = 0;
    __syncthreads();
    int r = blockIdx.x * 256 + tid;
    int e0 = tki[r * 2], e1 = tki[r * 2 + 1];
    int p0 = atomicAdd(&lcnt[e0], 1);
    int p1 = atomicAdd(&lcnt[e1], 1);
    __syncthreads();
    if (tid < NEXP) lbase[tid] = atomicAdd(&cursor[tid], lcnt[tid]);
    __syncthreads();
    list[lbase[e0] + p0] = r * 2;
    list[lbase[e1] + p1] = r * 2 + 1;
}

// ---------------------------------------------------------------------------
// Kernel 4: grouped expert GEMM, 32 gathered rows x 256 cols per block.
// A staged in LDS (swizzled, per-octet conflict-free). Epilogue transposes
// through the dead A-tile and stores contiguous bf16 rows to y0/y1.
// ---------------------------------------------------------------------------
__global__ __launch_bounds__(256) void moe_gemm_kernel(
    const unsigned short* __restrict__ xb, const unsigned short* __restrict__ wb,
    const float* __restrict__ expb, const float* __restrict__ tkp,
    const int* __restrict__ list, const int* __restrict__ tile_tab,
    unsigned short* __restrict__ y0, unsigned short* __restrict__ y1)
{
    // bijective XCD swizzle: NTILES = 2080 = 8 * 260
    int b = (blockIdx.x & 7) * (NTILES / 8) + (blockIdx.x >> 3);
    int hdr = tile_tab[b * 2];
    int e = hdr & 0xff, nr = hdr >> 8;
    if (nr == 0) return;
    int m0 = tile_tab[b * 2 + 1];

    __shared__ unsigned short xa[TROWS * 256];   // 16 KB, dual-use
    __shared__ int   srow[TROWS];
    __shared__ int   sslot[TROWS];
    __shared__ float sprob[TROWS];
    int tid = threadIdx.x;
    if (tid < TROWS) {
        if (tid < nr) {
            int ent = list[m0 + tid];
            srow[tid]  = ent >> 1;
            sslot[tid] = ent & 1;
            sprob[tid] = tkp[ent];
        } else { srow[tid] = -1; sslot[tid] = 0; sprob[tid] = 0.f; }
    }
    __syncthreads();

    // stage A: 8 threads/row; thread: row=tid>>3, 16B chunks (tid&7)+8i, swizzled
    {
        int r_ = tid >> 3;
        int gr = srow[r_]; if (gr < 0) gr = 0;
        const uint4* src = (const uint4*)(xb + (size_t)gr * D_INP);
        uint4* dst = (uint4*)xa;
        int swz = r_ & 7;
        #pragma unroll
        for (int i = 0; i < 4; ++i) {
            int c = (tid & 7) + 8 * i;
            dst[r_ * 32 + (c ^ swz)] = src[c];
        }
    }
    __syncthreads();

    int wave = tid >> 6;
    int lane = tid & 63;
    int lr = lane & 15;
    int kg = lane >> 4;
    int n0 = wave * 64;
    int aswz = lr & 7;

    f32x4 acc[2][4];
    #pragma unroll
    for (int mm = 0; mm < 2; mm++)
        #pragma unroll
        for (int nn = 0; nn < 4; nn++)
            acc[mm][nn] = (f32x4){0.f, 0.f, 0.f, 0.f};

    #pragma unroll
    for (int kk = 0; kk < 8; kk++) {
        int chunk = kk * 4 + kg;
        int aoff = (chunk ^ aswz) * 8;
        bf16x8 a[2], bb[4];
        #pragma unroll
        for (int mm = 0; mm < 2; mm++)
            a[mm] = *(const bf16x8*)&xa[(mm * 16 + lr) * 256 + aoff];
        #pragma unroll
        for (int nn = 0; nn < 4; nn++)
            bb[nn] = *(const bf16x8*)(wb + ((size_t)e * 256 + n0 + nn * 16 + lr) * D_INP + kk * 32 + kg * 8);
        #pragma unroll
        for (int mm = 0; mm < 2; mm++)
            #pragma unroll
            for (int nn = 0; nn < 4; nn++)
                acc[mm][nn] = __builtin_amdgcn_mfma_f32_16x16x32_bf16(a[mm], bb[nn], acc[mm][nn], 0, 0, 0);
    }
    __syncthreads();   // all A reads done; reuse xa as bf16 output staging

    // epilogue: (acc + bias) * prob -> bf16 into xa[row][col] (linear layout)
    {
        float bias[4];
        #pragma unroll
        for (int nn = 0; nn < 4; nn++) bias[nn] = expb[e * 256 + n0 + nn * 16 + lr];
        #pragma unroll
        for (int mm = 0; mm < 2; mm++) {
            #pragma unroll
            for (int j = 0; j < 4; j++) {
                int lrow = mm * 16 + kg * 4 + j;
                float pp = sprob[lrow];
                #pragma unroll
                for (int nn = 0; nn < 4; nn++) {
                    float v = (acc[mm][nn][j] + bias[nn]) * pp;
                    xa[lrow * 256 + n0 + nn * 16 + lr] = f2b(v);
                }
            }
        }
    }
    __syncthreads();

    // store: 8 threads/row, contiguous 16B chunks of the 512B bf16 row
    {
        int r_ = tid >> 3;
        int gr = srow[r_];
        if (gr >= 0) {
            unsigned short* dstb = (sslot[r_] ? y1 : y0) + (size_t)gr * D_OUTP;
            const uint4* src = (const uint4*)(xa + r_ * 256);
            uint4* dst = (uint4*)dstb;
            #pragma unroll
            for (int i = 0; i < 4; ++i) {
                int c = (tid & 7) + 8 * i;
                dst[c] = src[c];
            }
        }
    }
}

// ---------------------------------------------------------------------------
// Kernel 5: out = f32(y0) + f32(y1), streaming
// ---------------------------------------------------------------------------
__global__ __launch_bounds__(256) void combine_kernel(
    const unsigned short* __restrict__ y0, const unsigned short* __restrict__ y1,
    float* __restrict__ out)
{
    size_t i = ((size_t)blockIdx.x * 256 + threadIdx.x) * 8;
    uint4 a = *(const uint4*)(y0 + i);
    uint4 b = *(const uint4*)(y1 + i);
    const unsigned short* ap = (const unsigned short*)&a;
    const unsigned short* bp = (const unsigned short*)&b;
    float4 o0, o1;
    o0.x = b2f(ap[0]) + b2f(bp[0]);
    o0.y = b2f(ap[1]) + b2f(bp[1]);
    o0.z = b2f(ap[2]) + b2f(bp[2]);
    o0.w = b2f(ap[3]) + b2f(bp[3]);
    o1.x = b2f(ap[4]) + b2f(bp[4]);
    o1.y = b2f(ap[5]) + b2f(bp[5]);
    o1.z = b2f(ap[6]) + b2f(bp[6]);
    o1.w = b2f(ap[7]) + b2f(bp[7]);
    *(float4*)(out + i)     = o0;
    *(float4*)(out + i + 4) = o1;
}

// ---------------------------------------------------------------------------
extern "C" void kernel_launch(void* const* d_in, const int* in_sizes, int n_in,
                              void* d_out, int out_size, void* d_ws, size_t ws_size,
                              hipStream_t stream)
{
    const float* x   = (const float*)d_in[0];
    const float* noi = (const float*)d_in[1];
    const float* gw  = (const float*)d_in[2];
    const float* gb  = (const float*)d_in[3];
    const float* ew  = (const float*)d_in[4];
    const float* eb  = (const float*)d_in[5];
    float* out = (float*)d_out;

    char* p = (char*)d_ws;
    unsigned short* xb = (unsigned short*)p; p += (size_t)N_ROWS * D_INP * 2;
    unsigned short* wb = (unsigned short*)p; p += (size_t)NEXP * D_OUTP * D_INP * 2;
    unsigned short* y0 = (unsigned short*)p; p += (size_t)N_ROWS * D_OUTP * 2;
    unsigned short* y1 = (unsigned short*)p; p += (size_t)N_ROWS * D_OUTP * 2;
    float* tkp  = (float*)p; p += (size_t)N_ROWS * 2 * 4;
    int*   tki  = (int*)p;   p += (size_t)N_ROWS * 2 * 4;
    int*   list = (int*)p;   p += (size_t)N_ROWS * 2 * 4;
    int*   ttab = (int*)p;   p += (size_t)NTILES * 2 * 4;
    float* esum = (float*)p; p += 32 * 4;
    int*   ecnt = (int*)p;   p += 32 * 4;
    int*   offs = (int*)p;   p += 33 * 4;
    int*   curs = (int*)p;   p += 33 * 4;

    hipMemsetAsync(esum, 0, 64 * 4, stream);  // esum + ecnt

    gate_kernel<<<N_ROWS / 128, 256, 0, stream>>>(x, noi, gw, gb, ew, wb, xb, tkp, tki, esum, ecnt);
    scan_kernel<<<1, 256, 0, stream>>>(esum, ecnt, offs, curs, ttab, out + (size_t)N_ROWS * D_OUTP);
    build_list_kernel<<<N_ROWS / 256, 256, 0, stream>>>(tki, curs, list);
    moe_gemm_kernel<<<NTILES, 256, 0, stream>>>(xb, wb, eb, tkp, list, ttab, y0, y1);
    combine_kernel<<<N_ROWS * D_OUTP / 8 / 256, 256, 0, stream>>>(y0, y1, out);
}

// Round 6
// 152.716 us; speedup vs baseline: 2.1950x; 1.1729x over previous
//
#include <hip/hip_runtime.h>
#include <hip/hip_bf16.h>

#define N_ROWS 32768
#define D_INP  256
#define NEXP   32
#define D_OUTP 256
#define TROWS  32
#define NTILES 2080   // 8 * 260; max tiles = 65536/32 + 32
#define GROWS  64     // gate rows per block

typedef __attribute__((ext_vector_type(4))) float f32x4;
typedef __attribute__((ext_vector_type(8))) short bf16x8;

__device__ inline unsigned short f2b(float f) {
    union { __hip_bfloat16 h; unsigned short u; } cv;
    cv.h = __float2bfloat16(f);
    return cv.u;
}
__device__ inline float b2f(unsigned short u) {
    union { unsigned v; float f; } c; c.v = ((unsigned)u) << 16; return c.f;
}

// ---------------------------------------------------------------------------
// Kernel 1: gate GEMM (fp32 LDS-tiled) + softmax + top-2 + stats
// + fused bf16 cast of x + fused FRAGMENT-ORDER bf16 transpose of experts_w:
//   wbT[((e*4+q)*8+kk)*4+nn][lane=kg*16+lr] = W[e*256+q*64+nn*16+lr][kk*32+kg*8..+8]
// so moe_gemm B-loads are contiguous 1KB per wave instruction.
// 64 rows/block, grid 512, ~67KB LDS -> 2 blocks/CU.
// ---------------------------------------------------------------------------
__global__ __launch_bounds__(256) void gate_kernel(
    const float* __restrict__ x, const float* __restrict__ noise,
    const float* __restrict__ gw, const float* __restrict__ gb,
    const float* __restrict__ ew, unsigned short* __restrict__ wbT,
    unsigned short* __restrict__ xb, float* __restrict__ tkp,
    int* __restrict__ tki, float* __restrict__ esum, int* __restrict__ ecnt)
{
    __shared__ float gws[NEXP * 260];    // 33,280 B
    __shared__ float xs[GROWS * 132];    // 33,792 B
    __shared__ float lsum[NEXP];
    __shared__ int   lcnt[NEXP];

    int tid = threadIdx.x;
    int row0 = blockIdx.x * GROWS;

    // stage gw: 2048 float4, 8 per thread
    #pragma unroll
    for (int it = 0; it < 8; ++it) {
        int q = it * 256 + tid;
        int e = q >> 6;
        int k = (q & 63) * 4;
        float4 v = ((const float4*)gw)[q];
        *(float4*)&gws[e * 260 + k] = v;
    }
    if (tid < NEXP) { lsum[tid] = 0.f; lcnt[tid] = 0; }

    int e4 = tid & 7;
    int rq = tid >> 3;   // 0..31

    float acc[2][4];
    #pragma unroll
    for (int m = 0; m < 2; m++)
        #pragma unroll
        for (int n = 0; n < 4; n++) acc[m][n] = 0.f;

    for (int h = 0; h < 2; ++h) {
        int ko = h * 128;
        __syncthreads();
        // stage xs: 64 rows x 32 float4 = 2048, 8 per thread; fused bf16 cast
        #pragma unroll
        for (int it = 0; it < 8; ++it) {
            int idx = it * 256 + tid;
            int r = idx >> 5;
            int f = idx & 31;
            float4 v = *(const float4*)(x + (size_t)(row0 + r) * D_INP + ko + f * 4);
            *(float4*)&xs[r * 132 + f * 4] = v;
            unsigned short b[4] = { f2b(v.x), f2b(v.y), f2b(v.z), f2b(v.w) };
            *(ushort4*)(xb + (size_t)(row0 + r) * D_INP + ko + f * 4) = *(ushort4*)b;
        }
        __syncthreads();
        #pragma unroll 4
        for (int c = 0; c < 32; ++c) {
            float4 xv[2], wv[4];
            #pragma unroll
            for (int m = 0; m < 2; m++)
                xv[m] = *(float4*)&xs[(rq + 32 * m) * 132 + c * 4];
            #pragma unroll
            for (int n = 0; n < 4; n++)
                wv[n] = *(float4*)&gws[(e4 + 8 * n) * 260 + ko + c * 4];
            #pragma unroll
            for (int m = 0; m < 2; m++)
                #pragma unroll
                for (int n = 0; n < 4; n++)
                    acc[m][n] = fmaf(xv[m].x, wv[n].x,
                                fmaf(xv[m].y, wv[n].y,
                                fmaf(xv[m].z, wv[n].z,
                                fmaf(xv[m].w, wv[n].w, acc[m][n]))));
        }
    }

    #pragma unroll
    for (int m = 0; m < 2; m++) {
        int R = row0 + rq + 32 * m;
        float l[4], p[4];
        #pragma unroll
        for (int n = 0; n < 4; n++) {
            int E = e4 + 8 * n;
            l[n] = acc[m][n] + gb[E] + 0.1f * noise[(size_t)R * NEXP + E];
        }
        float mx = fmaxf(fmaxf(l[0], l[1]), fmaxf(l[2], l[3]));
        #pragma unroll
        for (int s = 1; s < 8; s <<= 1) mx = fmaxf(mx, __shfl_xor(mx, s));
        float sum = 0.f;
        #pragma unroll
        for (int n = 0; n < 4; n++) { p[n] = expf(l[n] - mx); sum += p[n]; }
        #pragma unroll
        for (int s = 1; s < 8; s <<= 1) sum += __shfl_xor(sum, s);
        float inv = 1.f / sum;
        #pragma unroll
        for (int n = 0; n < 4; n++) p[n] *= inv;

        // top-1 (ties -> lower expert index)
        float bp = p[0]; int bi = e4;
        #pragma unroll
        for (int n = 1; n < 4; n++) if (p[n] > bp) { bp = p[n]; bi = e4 + 8 * n; }
        #pragma unroll
        for (int s = 1; s < 8; s <<= 1) {
            float op = __shfl_xor(bp, s); int oi = __shfl_xor(bi, s);
            if (op > bp || (op == bp && oi < bi)) { bp = op; bi = oi; }
        }
        // top-2
        float bp2 = -1.f; int bi2 = 0;
        #pragma unroll
        for (int n = 0; n < 4; n++) {
            int E = e4 + 8 * n;
            float q = (E == bi) ? -1.f : p[n];
            if (q > bp2 || (q == bp2 && E < bi2)) { bp2 = q; bi2 = E; }
        }
        #pragma unroll
        for (int s = 1; s < 8; s <<= 1) {
            float op = __shfl_xor(bp2, s); int oi = __shfl_xor(bi2, s);
            if (op > bp2 || (op == bp2 && oi < bi2)) { bp2 = op; bi2 = oi; }
        }
        if (e4 == 0) {
            tkp[R * 2] = bp;  tkp[R * 2 + 1] = bp2;
            tki[R * 2] = bi;  tki[R * 2 + 1] = bi2;
            atomicAdd(&lcnt[bi], 1); atomicAdd(&lcnt[bi2], 1);
        }
        #pragma unroll
        for (int n = 0; n < 4; n++) atomicAdd(&lsum[e4 + 8 * n], p[n]);
    }

    // fused experts_w fragment transpose: 262144 fragments total, 512/block, 2/thread
    #pragma unroll
    for (int it = 0; it < 2; ++it) {
        int fid = blockIdx.x * 512 + it * 256 + tid;
        int row = fid >> 5;        // [0, 8192): W output-row = out col
        int kc  = fid & 31;        // 8-wide k chunk
        const float4* s = (const float4*)(ew + (size_t)row * D_INP + kc * 8);
        float4 v0 = s[0], v1 = s[1];
        unsigned short t[8] = { f2b(v0.x), f2b(v0.y), f2b(v0.z), f2b(v0.w),
                                f2b(v1.x), f2b(v1.y), f2b(v1.z), f2b(v1.w) };
        int e  = row >> 8;
        int rr = row & 255;
        int q  = rr >> 6;
        int nn = (rr >> 4) & 3;
        int lr = rr & 15;
        int kk = kc >> 2;
        int kg = kc & 3;
        size_t off = ((((size_t)(e * 4 + q) * 8 + kk) * 4 + nn) * 64 + kg * 16 + lr) * 8;
        *(uint4*)(wbT + off) = *(uint4*)t;
    }

    __syncthreads();
    if (tid < NEXP) {
        unsafeAtomicAdd(&esum[tid], lsum[tid]);
        atomicAdd(&ecnt[tid], lcnt[tid]);
    }
}

// ---------------------------------------------------------------------------
// Kernel 2: scatter (row,slot) into per-expert lists; local scan of ecnt
// (no separate scan kernel); block 0 also computes the load-balance loss.
// 32 blocks x 1024 threads.
// ---------------------------------------------------------------------------
__global__ __launch_bounds__(1024) void build_list_kernel(
    const int* __restrict__ tki, const float* __restrict__ esum,
    const int* __restrict__ ecnt, int* __restrict__ cursor0,
    int* __restrict__ list, float* __restrict__ loss_out)
{
    __shared__ int lcnt[NEXP], lbase[NEXP], s_offs[NEXP + 1];
    int tid = threadIdx.x;
    if (tid < NEXP) lcnt[tid] = 0;
    if (tid < 32) {
        int c = ecnt[tid];
        int ic = c;
        #pragma unroll
        for (int s = 1; s < 32; s <<= 1) {
            int a = __shfl_up(ic, s, 32);
            if (tid >= s) ic += a;
        }
        s_offs[tid + 1] = ic;
        if (tid == 0) s_offs[0] = 0;
    }
    __syncthreads();
    int r = blockIdx.x * 1024 + tid;
    int e0 = tki[r * 2], e1 = tki[r * 2 + 1];
    int p0 = atomicAdd(&lcnt[e0], 1);
    int p1 = atomicAdd(&lcnt[e1], 1);
    __syncthreads();
    if (tid < NEXP) lbase[tid] = s_offs[tid] + atomicAdd(&cursor0[tid], lcnt[tid]);
    __syncthreads();
    list[lbase[e0] + p0] = r * 2;
    list[lbase[e1] + p1] = r * 2 + 1;

    if (blockIdx.x == 0 && tid < 32) {
        float d = esum[tid] * (1.f / N_ROWS) - (1.f / NEXP);
        float v = d * d;
        #pragma unroll
        for (int s = 16; s > 0; s >>= 1) v += __shfl_xor(v, s, 32);
        if (tid == 0) *loss_out = v;
    }
}

// ---------------------------------------------------------------------------
// Kernel 3: grouped expert GEMM, 32 gathered rows x 256 cols per block.
// Tile descriptor from a local 32-wide scan of ecnt (no tile table).
// B loads from fragment-order wbT: one contiguous 1KB per wave instruction.
// A staged in LDS (chunk-XOR swizzle). bf16 epilogue via LDS -> y0/y1.
// ---------------------------------------------------------------------------
__global__ __launch_bounds__(256) void moe_gemm_kernel(
    const unsigned short* __restrict__ xb, const unsigned short* __restrict__ wbT,
    const float* __restrict__ expb, const float* __restrict__ tkp,
    const int* __restrict__ list, const int* __restrict__ ecnt,
    unsigned short* __restrict__ y0, unsigned short* __restrict__ y1)
{
    __shared__ int s_offs[NEXP + 1], s_toff[NEXP + 1];
    __shared__ unsigned short xa[TROWS * 256];   // 16 KB, dual-use
    __shared__ int   srow[TROWS];
    __shared__ int   sslot[TROWS];
    __shared__ float sprob[TROWS];

    int tid = threadIdx.x;
    if (tid < 32) {
        int c = ecnt[tid];
        int ic = c, itc = (c + TROWS - 1) >> 5;
        #pragma unroll
        for (int s = 1; s < 32; s <<= 1) {
            int a  = __shfl_up(ic, s, 32);  if (tid >= s) ic += a;
            int b2 = __shfl_up(itc, s, 32); if (tid >= s) itc += b2;
        }
        s_offs[tid + 1] = ic; s_toff[tid + 1] = itc;
        if (tid == 0) { s_offs[0] = 0; s_toff[0] = 0; }
    }
    __syncthreads();

    // bijective XCD swizzle: NTILES = 8 * 260
    int b = (blockIdx.x & 7) * (NTILES / 8) + (blockIdx.x >> 3);
    if (b >= s_toff[NEXP]) return;   // uniform exit, no barriers below missed
    int e = 0;
    #pragma unroll
    for (int s = 16; s; s >>= 1)
        if (e + s <= 31 && s_toff[e + s] <= b) e += s;
    int m0 = s_offs[e] + (b - s_toff[e]) * TROWS;
    int nr = min(TROWS, s_offs[e + 1] - m0);

    if (tid < TROWS) {
        if (tid < nr) {
            int ent = list[m0 + tid];
            srow[tid]  = ent >> 1;
            sslot[tid] = ent & 1;
            sprob[tid] = tkp[ent];
        } else { srow[tid] = -1; sslot[tid] = 0; sprob[tid] = 0.f; }
    }
    __syncthreads();

    // stage A: 8 threads/row; 16B chunks (tid&7)+8i, chunk-XOR swizzled
    {
        int r_ = tid >> 3;
        int gr = srow[r_]; if (gr < 0) gr = 0;
        const uint4* src = (const uint4*)(xb + (size_t)gr * D_INP);
        uint4* dst = (uint4*)xa;
        int swz = r_ & 7;
        #pragma unroll
        for (int i = 0; i < 4; ++i) {
            int c = (tid & 7) + 8 * i;
            dst[r_ * 32 + (c ^ swz)] = src[c];
        }
    }
    __syncthreads();

    int wave = tid >> 6;
    int lane = tid & 63;
    int lr = lane & 15;
    int kg = lane >> 4;
    int n0 = wave * 64;
    int aswz = lr & 7;

    const unsigned short* wbase = wbT + (size_t)(e * 4 + wave) * 32 * 512;

    f32x4 acc[2][4];
    #pragma unroll
    for (int mm = 0; mm < 2; mm++)
        #pragma unroll
        for (int nn = 0; nn < 4; nn++)
            acc[mm][nn] = (f32x4){0.f, 0.f, 0.f, 0.f};

    #pragma unroll
    for (int kk = 0; kk < 8; kk++) {
        int chunk = kk * 4 + kg;
        int aoff = (chunk ^ aswz) * 8;
        bf16x8 a[2], bb[4];
        #pragma unroll
        for (int mm = 0; mm < 2; mm++)
            a[mm] = *(const bf16x8*)&xa[(mm * 16 + lr) * 256 + aoff];
        #pragma unroll
        for (int nn = 0; nn < 4; nn++)
            bb[nn] = *(const bf16x8*)(wbase + (kk * 4 + nn) * 512 + lane * 8);
        #pragma unroll
        for (int mm = 0; mm < 2; mm++)
            #pragma unroll
            for (int nn = 0; nn < 4; nn++)
                acc[mm][nn] = __builtin_amdgcn_mfma_f32_16x16x32_bf16(a[mm], bb[nn], acc[mm][nn], 0, 0, 0);
    }
    __syncthreads();   // A reads done; reuse xa for bf16 output staging

    // epilogue: (acc + bias) * prob -> bf16 into xa[row][col]
    {
        float bias[4];
        #pragma unroll
        for (int nn = 0; nn < 4; nn++) bias[nn] = expb[e * 256 + n0 + nn * 16 + lr];
        #pragma unroll
        for (int mm = 0; mm < 2; mm++) {
            #pragma unroll
            for (int j = 0; j < 4; j++) {
                int lrow = mm * 16 + kg * 4 + j;
                float pp = sprob[lrow];
                #pragma unroll
                for (int nn = 0; nn < 4; nn++) {
                    float v = (acc[mm][nn][j] + bias[nn]) * pp;
                    xa[lrow * 256 + n0 + nn * 16 + lr] = f2b(v);
                }
            }
        }
    }
    __syncthreads();

    // store: 8 threads/row, contiguous 16B chunks of the 512B bf16 row
    {
        int r_ = tid >> 3;
        int gr = srow[r_];
        if (gr >= 0) {
            unsigned short* dstb = (sslot[r_] ? y1 : y0) + (size_t)gr * D_OUTP;
            const uint4* src = (const uint4*)(xa + r_ * 256);
            uint4* dst = (uint4*)dstb;
            #pragma unroll
            for (int i = 0; i < 4; ++i) {
                int c = (tid & 7) + 8 * i;
                dst[c] = src[c];
            }
        }
    }
}

// ---------------------------------------------------------------------------
// Kernel 4: out = f32(y0) + f32(y1), streaming
// ---------------------------------------------------------------------------
__global__ __launch_bounds__(256) void combine_kernel(
    const unsigned short* __restrict__ y0, const unsigned short* __restrict__ y1,
    float* __restrict__ out)
{
    size_t i = ((size_t)blockIdx.x * 256 + threadIdx.x) * 8;
    uint4 a = *(const uint4*)(y0 + i);
    uint4 b = *(const uint4*)(y1 + i);
    const unsigned short* ap = (const unsigned short*)&a;
    const unsigned short* bp = (const unsigned short*)&b;
    float4 o0, o1;
    o0.x = b2f(ap[0]) + b2f(bp[0]);
    o0.y = b2f(ap[1]) + b2f(bp[1]);
    o0.z = b2f(ap[2]) + b2f(bp[2]);
    o0.w = b2f(ap[3]) + b2f(bp[3]);
    o1.x = b2f(ap[4]) + b2f(bp[4]);
    o1.y = b2f(ap[5]) + b2f(bp[5]);
    o1.z = b2f(ap[6]) + b2f(bp[6]);
    o1.w = b2f(ap[7]) + b2f(bp[7]);
    *(float4*)(out + i)     = o0;
    *(float4*)(out + i + 4) = o1;
}

// ---------------------------------------------------------------------------
extern "C" void kernel_launch(void* const* d_in, const int* in_sizes, int n_in,
                              void* d_out, int out_size, void* d_ws, size_t ws_size,
                              hipStream_t stream)
{
    const float* x   = (const float*)d_in[0];
    const float* noi = (const float*)d_in[1];
    const float* gw  = (const float*)d_in[2];
    const float* gb  = (const float*)d_in[3];
    const float* ew  = (const float*)d_in[4];
    const float* eb  = (const float*)d_in[5];
    float* out = (float*)d_out;

    char* p = (char*)d_ws;
    unsigned short* xb  = (unsigned short*)p; p += (size_t)N_ROWS * D_INP * 2;
    unsigned short* wbT = (unsigned short*)p; p += (size_t)NEXP * D_OUTP * D_INP * 2;
    unsigned short* y0  = (unsigned short*)p; p += (size_t)N_ROWS * D_OUTP * 2;
    unsigned short* y1  = (unsigned short*)p; p += (size_t)N_ROWS * D_OUTP * 2;
    float* tkp  = (float*)p; p += (size_t)N_ROWS * 2 * 4;
    int*   tki  = (int*)p;   p += (size_t)N_ROWS * 2 * 4;
    int*   list = (int*)p;   p += (size_t)N_ROWS * 2 * 4;
    float* esum = (float*)p; p += 32 * 4;
    int*   ecnt = (int*)p;   p += 32 * 4;
    int*   cur0 = (int*)p;   p += 32 * 4;

    hipMemsetAsync(esum, 0, 3 * 32 * 4, stream);   // esum + ecnt + cursor0

    gate_kernel<<<N_ROWS / GROWS, 256, 0, stream>>>(x, noi, gw, gb, ew, wbT, xb, tkp, tki, esum, ecnt);
    build_list_kernel<<<N_ROWS / 1024, 1024, 0, stream>>>(tki, esum, ecnt, cur0, list, out + (size_t)N_ROWS * D_OUTP);
    moe_gemm_kernel<<<NTILES, 256, 0, stream>>>(xb, wbT, eb, tkp, list, ecnt, y0, y1);
    combine_kernel<<<N_ROWS * D_OUTP / 8 / 256, 256, 0, stream>>>(y0, y1, out);
}